// Round 4
// baseline (1427.479 us; speedup 1.0000x reference)
//
#include <hip/hip_runtime.h>
#include <math.h>

// Problem constants (B=4096, T=100, F=13, H=100)
#define B_    4096
#define T_    100
#define F_    13
#define H_    100

typedef short bf16x8 __attribute__((ext_vector_type(8)));
typedef float f32x4  __attribute__((ext_vector_type(4)));

// ---- ws layout (bytes), total 651,264 ----
#define O_HIST   0u        // 512
#define O_ROWMAP 512u      // 4096*4
#define O_BIAS0  16896u    // 448*4
#define O_BIAS1  18688u    // 448*4
#define O_B0     20480u    // 4kt * 28672 u16 * 2B = 229376
#define O_B1     249856u   // 7kt * 28672 u16 * 2B = 401408 -> 651264

// B-fragment array layout (u16 units), per layer:
//   idx = (((kt*4 + g)*7 + ct)*2 + pass)*512 + lane*8 + j
// where lane's frag element j holds W_pass[k = kt*32 + (lane>>4)*8 + j]
//                                  [col = g*112 + ct*16 + (lane&15)]
// (cols are gate-major with H padded 100->112; pad cols/k are zero)

__device__ __forceinline__ float sigmoid_f(float v) {
    return 1.0f / (1.0f + __expf(-v));
}
__device__ __forceinline__ float tanh_f(float v) {
    float e = __expf(2.0f * v);
    return 1.0f - 2.0f / (e + 1.0f);
}
// fp32 -> bf16 hi (truncate) + lo (RNE of remainder): hi+lo ~ 2^-17 rel err
__device__ __forceinline__ void split_bf16(float v, unsigned short& hi, unsigned short& lo) {
    unsigned u = __float_as_uint(v);
    hi = (unsigned short)(u >> 16);
    float hf = __uint_as_float(u & 0xFFFF0000u);
    float rem = v - hf;
    unsigned r = __float_as_uint(rem);
    unsigned rnd = r + 0x7FFFu + ((r >> 16) & 1u);
    lo = (unsigned short)(rnd >> 16);
}
__device__ __forceinline__ float bf16_to_f(unsigned short b) {
    return __uint_as_float(((unsigned)b) << 16);
}

// ---------------- prep: counting sort of rows by length ----------------
__global__ void k_hist(const int* __restrict__ len, int* __restrict__ hist) {
    int b = blockIdx.x * blockDim.x + threadIdx.x;
    if (b < B_) atomicAdd(&hist[len[b]], 1);
}
__global__ void k_scan(int* __restrict__ hist) {
    if (threadIdx.x == 0 && blockIdx.x == 0) {
        int acc = 0;
        for (int l = 0; l <= 100; ++l) { int c = hist[l]; hist[l] = acc; acc += c; }
    }
}
__global__ void k_scatter(const int* __restrict__ len, int* __restrict__ hist,
                          int* __restrict__ rowmap) {
    int b = blockIdx.x * blockDim.x + threadIdx.x;
    if (b < B_) {
        int pos = atomicAdd(&hist[len[b]], 1);
        rowmap[pos] = b;
    }
}

// ---------------- prep: biases (gate-major, padded) ----------------
__global__ void k_prep_bias(const float* __restrict__ bih0, const float* __restrict__ bhh0,
                            const float* __restrict__ bih1, const float* __restrict__ bhh1,
                            float* __restrict__ bias0, float* __restrict__ bias1) {
    int idx = blockIdx.x * blockDim.x + threadIdx.x;
    if (idx < 448) {
        int g = idx / 112, cell = idx % 112;
        float v0 = 0.f, v1 = 0.f;
        if (cell < 100) {
            int row = g * 100 + cell;
            v0 = bih0[row] + bhh0[row];
            v1 = bih1[row] + bhh1[row];
        }
        bias0[idx] = v0; bias1[idx] = v1;
    }
}

// ---------------- prep: weights into B-fragment order, bf16 hi/lo ----------
// Layer0 A-k: k<100 -> h0 (Whh0), 100..112 -> x (Wih0), >=113 -> 0
// Layer1 A-k: k<100 -> h0n (Wih1), 100..199 -> h1 (Whh1), >=200 -> 0
__global__ void k_prep_b(const float* __restrict__ Wih0, const float* __restrict__ Whh0,
                         const float* __restrict__ Wih1, const float* __restrict__ Whh1,
                         unsigned short* __restrict__ B0, unsigned short* __restrict__ B1) {
    const int PER_KT = 4 * 7 * 2 * 512;  // 28672 u16 per K-tile
    int idx = blockIdx.x * blockDim.x + threadIdx.x;
    if (idx >= 7 * PER_KT) return;
    int kt = idx / PER_KT;
    int s  = idx % PER_KT;
    int g  = s / 7168;
    int s2 = s % 7168;
    int ct = s2 / 1024;
    int s3 = s2 % 1024;
    int pass = s3 / 512;
    int e  = s3 % 512;
    int lane = e >> 3, j = e & 7;
    int n = lane & 15, q = lane >> 4;
    int k = kt * 32 + q * 8 + j;
    int cell = ct * 16 + n;

    unsigned short hi, lo;
    {   // layer 1
        float w = 0.f;
        if (cell < 100) {
            int row = g * 100 + cell;
            if (k < 100)      w = Wih1[row * 100 + k];
            else if (k < 200) w = Whh1[row * 100 + (k - 100)];
        }
        split_bf16(w, hi, lo);
        B1[idx] = pass ? lo : hi;
    }
    if (kt < 4) {  // layer 0
        float w = 0.f;
        if (cell < 100) {
            int row = g * 100 + cell;
            if (k < 100)      w = Whh0[row * 100 + k];
            else if (k < 113) w = Wih0[row * 13 + (k - 100)];
        }
        split_bf16(w, hi, lo);
        B0[idx] = pass ? lo : hi;
    }
}

// ---------------- main persistent MFMA LSTM ----------------
// v5: 256 blocks x 16 rows (v4 structure) + restructured GEMM inner loop:
//  * kt-granular double-buffered B prefetch: all 8 fragments (bh/bl x 4 gates)
//    of kt+1 are issued before kt's MFMAs -> ~150-190 cyc of latency cover
//    (was ~50 cyc with (kt,g)-pair-deep prefetch).
//  * MFMAs interleaved g-major: consecutive MFMAs target different
//    accumulators (dependency distance 4), so the in-order wave never stalls
//    on MFMA result latency (was 3 serially-chained MFMAs per iteration).
//  * Per-accumulator MFMA order unchanged (ah*bl, al*bh, ah*bh, kt ascending)
//    -> bit-identical numerics vs v3/v4 (absmax canary: 0.0001220703).
//  * Register audit: P 16 + B-dbuf 64 + A 8 + state ~32 = ~120 < 128 cap.
// Waves 0..6: cell-tile ct (cells 16ct..16ct+15), all 4 gates. Wave 7: x.
__global__ __attribute__((amdgpu_flat_work_group_size(512, 512), amdgpu_waves_per_eu(2, 2)))
void k_lstm(
    const float* __restrict__ x, const int* __restrict__ lengths,
    const int* __restrict__ rowmap,
    const unsigned short* __restrict__ B0, const unsigned short* __restrict__ B1,
    const float* __restrict__ bias0, const float* __restrict__ bias1,
    const float* __restrict__ Wfc, const float* __restrict__ bfc,
    float* __restrict__ out)
{
    // strides padded (+8 u16) so frag reads are 2-way-conflict max (free)
    __shared__ __align__(16) unsigned short Ah0[2][16 * 136];
    __shared__ __align__(16) unsigned short Al0[2][16 * 136];
    __shared__ __align__(16) unsigned short Ah1[2][16 * 232];
    __shared__ __align__(16) unsigned short Al1[2][16 * 232];
    __shared__ int sRow[16], sLen[16], sTmax;

    const int tid = threadIdx.x;
    const int wv = tid >> 6, lane = tid & 63;

    if (tid < 16) {
        int r = rowmap[blockIdx.x * 16 + tid];
        sRow[tid] = r; sLen[tid] = lengths[r];
    }
    for (int i = tid; i < 16 * 136; i += 512) {
        Ah0[0][i] = 0; Al0[0][i] = 0; Ah0[1][i] = 0; Al0[1][i] = 0;
    }
    for (int i = tid; i < 16 * 232; i += 512) {
        Ah1[0][i] = 0; Al1[0][i] = 0; Ah1[1][i] = 0; Al1[1][i] = 0;
    }
    __syncthreads();   // (pre-1) sRow/sLen + zero-init published
    if (tid == 0) { int m = 0; for (int i = 0; i < 16; ++i) m = max(m, sLen[i]); sTmax = m; }

    // ---- per-wave setup ----
    const int ct = wv, n = lane & 15, q = lane >> 4;
    const int cell = ct * 16 + n;

    float b0v[4], b1v[4];
    int   lenR[4];
    float c0[4], c1[4];
    int offA0, offA1;
    const unsigned short* B0w = B0 + ct * 1024 + lane * 8;
    const unsigned short* B1w = B1 + ct * 1024 + lane * 8;
    if (wv < 7) {
#pragma unroll
        for (int g = 0; g < 4; ++g) {
            b0v[g] = bias0[g * 112 + cell];
            b1v[g] = bias1[g * 112 + cell];
        }
        offA0 = n * 136 + q * 8;
        offA1 = n * 232 + q * 8;
#pragma unroll
        for (int r = 0; r < 4; ++r) {
            lenR[r] = sLen[q * 4 + r];       // C row = q*4 + r
            c0[r] = 0.f; c1[r] = 0.f;
        }
    }

    // wave 7: x loader (16 rows x 13 feats = 208 slots, 4 per lane)
    int xvalid[4]; size_t xg[4]; int xa[4]; float xv[4];
    if (wv == 7) {
#pragma unroll
        for (int i = 0; i < 4; ++i) {
            int e = i * 64 + lane;
            xvalid[i] = (e < 208);
            int r = xvalid[i] ? (e / 13) : 0;
            int f = xvalid[i] ? (e - 13 * r) : 0;
            xg[i] = (size_t)sRow[r] * (T_ * F_) + f;
            xa[i] = r * 136 + 100 + f;
            xv[i] = xvalid[i] ? x[xg[i]] : 0.f;   // t = 0
        }
    }
    __syncthreads();   // (pre-2) sTmax published; zero-init done everywhere
    const int Tmax = sTmax;
    if (wv == 7) {     // write x_0 into buffer 0
#pragma unroll
        for (int i = 0; i < 4; ++i) if (xvalid[i]) {
            unsigned short hi, lo; split_bf16(xv[i], hi, lo);
            Ah0[0][xa[i]] = hi; Al0[0][xa[i]] = lo;
        }
    }
    __syncthreads();   // (pre-3) x_0 published

    for (int t = 0; t < Tmax; ++t) {
        const int p = t & 1, pn = p ^ 1;
        // =============== phase 1: layer-0 (reads A0[p]) ===============
        if (wv < 7) {
            f32x4 P[4];
#pragma unroll
            for (int g = 0; g < 4; ++g)
                P[g] = (f32x4){b0v[g], b0v[g], b0v[g], b0v[g]};
            bf16x8 bh[2][4], bl[2][4];
#pragma unroll
            for (int g = 0; g < 4; ++g) {           // preload kt=0 slice
                bh[0][g] = *(const bf16x8*)&B0w[g * 7168];
                bl[0][g] = *(const bf16x8*)&B0w[g * 7168 + 512];
            }
#pragma unroll
            for (int kt = 0; kt < 4; ++kt) {
                const int cb = kt & 1, nb = cb ^ 1;
                if (kt + 1 < 4) {                   // prefetch kt+1 slice
#pragma unroll
                    for (int g = 0; g < 4; ++g) {
                        bh[nb][g] = *(const bf16x8*)&B0w[((kt + 1) * 4 + g) * 7168];
                        bl[nb][g] = *(const bf16x8*)&B0w[((kt + 1) * 4 + g) * 7168 + 512];
                    }
                }
                bf16x8 ah = *(const bf16x8*)&Ah0[p][offA0 + kt * 32];
                bf16x8 al = *(const bf16x8*)&Al0[p][offA0 + kt * 32];
                // g-major interleave: dep distance 4 between MFMAs on same acc
#pragma unroll
                for (int g = 0; g < 4; ++g)
                    P[g] = __builtin_amdgcn_mfma_f32_16x16x32_bf16(ah, bl[cb][g], P[g], 0, 0, 0);
#pragma unroll
                for (int g = 0; g < 4; ++g)
                    P[g] = __builtin_amdgcn_mfma_f32_16x16x32_bf16(al, bh[cb][g], P[g], 0, 0, 0);
#pragma unroll
                for (int g = 0; g < 4; ++g)
                    P[g] = __builtin_amdgcn_mfma_f32_16x16x32_bf16(ah, bh[cb][g], P[g], 0, 0, 0);
            }
            // pointwise + state update
            float hreg[4];
#pragma unroll
            for (int r = 0; r < 4; ++r) {
                float zi = P[0][r];
                float zf = P[1][r];
                float zg = P[2][r];
                float zo = P[3][r];
                float cn = sigmoid_f(zf) * c0[r] + sigmoid_f(zi) * tanh_f(zg);
                float hn = sigmoid_f(zo) * tanh_f(cn);
                if (t < lenR[r]) c0[r] = cn;
                hreg[r] = hn;
            }
            // h0n -> A0[pn] (for GEMM0 at t+1) and A1[p] (for GEMM1 this step)
            if (cell < 100) {
#pragma unroll
                for (int r = 0; r < 4; ++r) {
                    if (t < lenR[r]) {
                        int m = q * 4 + r;
                        unsigned short hi, lo; split_bf16(hreg[r], hi, lo);
                        Ah0[pn][m * 136 + cell] = hi; Al0[pn][m * 136 + cell] = lo;
                        Ah1[p][m * 232 + cell]  = hi; Al1[p][m * 232 + cell]  = lo;
                    }
                }
            }
        } else {
            // wave 7: load x(t+1) and write into A0[pn] (read next at t+1)
            if (t + 1 < Tmax) {
#pragma unroll
                for (int i = 0; i < 4; ++i)
                    if (xvalid[i]) xv[i] = x[xg[i] + (size_t)(t + 1) * F_];
#pragma unroll
                for (int i = 0; i < 4; ++i) if (xvalid[i]) {
                    unsigned short hi, lo; split_bf16(xv[i], hi, lo);
                    Ah0[pn][xa[i]] = hi; Al0[pn][xa[i]] = lo;
                }
            }
        }
        __syncthreads();   // (A) h0n published in A1[p]
        // =============== phase 2: layer-1 (reads A1[p]) ===============
        if (wv < 7) {
            f32x4 P[4];
#pragma unroll
            for (int g = 0; g < 4; ++g)
                P[g] = (f32x4){b1v[g], b1v[g], b1v[g], b1v[g]};
            bf16x8 bh[2][4], bl[2][4];
#pragma unroll
            for (int g = 0; g < 4; ++g) {           // preload kt=0 slice
                bh[0][g] = *(const bf16x8*)&B1w[g * 7168];
                bl[0][g] = *(const bf16x8*)&B1w[g * 7168 + 512];
            }
#pragma unroll
            for (int kt = 0; kt < 7; ++kt) {
                const int cb = kt & 1, nb = cb ^ 1;
                if (kt + 1 < 7) {                   // prefetch kt+1 slice
#pragma unroll
                    for (int g = 0; g < 4; ++g) {
                        bh[nb][g] = *(const bf16x8*)&B1w[((kt + 1) * 4 + g) * 7168];
                        bl[nb][g] = *(const bf16x8*)&B1w[((kt + 1) * 4 + g) * 7168 + 512];
                    }
                }
                bf16x8 ah = *(const bf16x8*)&Ah1[p][offA1 + kt * 32];
                bf16x8 al = *(const bf16x8*)&Al1[p][offA1 + kt * 32];
#pragma unroll
                for (int g = 0; g < 4; ++g)
                    P[g] = __builtin_amdgcn_mfma_f32_16x16x32_bf16(ah, bl[cb][g], P[g], 0, 0, 0);
#pragma unroll
                for (int g = 0; g < 4; ++g)
                    P[g] = __builtin_amdgcn_mfma_f32_16x16x32_bf16(al, bh[cb][g], P[g], 0, 0, 0);
#pragma unroll
                for (int g = 0; g < 4; ++g)
                    P[g] = __builtin_amdgcn_mfma_f32_16x16x32_bf16(ah, bh[cb][g], P[g], 0, 0, 0);
            }
            float hreg[4];
#pragma unroll
            for (int r = 0; r < 4; ++r) {
                float zi = P[0][r];
                float zf = P[1][r];
                float zg = P[2][r];
                float zo = P[3][r];
                float cn = sigmoid_f(zf) * c1[r] + sigmoid_f(zi) * tanh_f(zg);
                float hn = sigmoid_f(zo) * tanh_f(cn);
                if (t < lenR[r]) c1[r] = cn;
                hreg[r] = hn;
            }
            // h1n -> A1[pn] (read at t+1); frozen rows keep last value in
            // buffer (len&1)
            if (cell < 100) {
#pragma unroll
                for (int r = 0; r < 4; ++r) {
                    if (t < lenR[r]) {
                        int m = q * 4 + r;
                        unsigned short hi, lo; split_bf16(hreg[r], hi, lo);
                        Ah1[pn][m * 232 + 100 + cell] = hi;
                        Al1[pn][m * 232 + 100 + cell] = lo;
                    }
                }
            }
        }
        __syncthreads();   // (B) A0[pn] (h0n+x) and A1[pn] (h1n) published
    }

    // final: out[b] = W_fc . h1 + b_fc  (h1 = hi+lo, frozen at len-1; it lives
    // in buffer len&1 since the last write at t=len-1 targeted parity (len-1)^1)
    if (tid < 16) {
        const int par = sLen[tid] & 1;
        float s = bfc[0];
        for (int j = 0; j < 100; ++j) {
            float h = bf16_to_f(Ah1[par][tid * 232 + 100 + j]) +
                      bf16_to_f(Al1[par][tid * 232 + 100 + j]);
            s = fmaf(Wfc[j], h, s);
        }
        out[sRow[tid]] = s;
    }
}

// ---------------- launch ----------------
extern "C" void kernel_launch(void* const* d_in, const int* in_sizes, int n_in,
                              void* d_out, int out_size, void* d_ws, size_t ws_size,
                              hipStream_t stream) {
    const float* x    = (const float*)d_in[0];
    const int*   len  = (const int*)d_in[1];
    const float* Wih0 = (const float*)d_in[2];
    const float* Whh0 = (const float*)d_in[3];
    const float* bih0 = (const float*)d_in[4];
    const float* bhh0 = (const float*)d_in[5];
    const float* Wih1 = (const float*)d_in[6];
    const float* Whh1 = (const float*)d_in[7];
    const float* bih1 = (const float*)d_in[8];
    const float* bhh1 = (const float*)d_in[9];
    const float* Wfc  = (const float*)d_in[10];
    const float* bfc  = (const float*)d_in[11];
    float* out = (float*)d_out;

    char* ws = (char*)d_ws;   // uses 651,264 bytes
    int*            hist   = (int*)(ws + O_HIST);
    int*            rowmap = (int*)(ws + O_ROWMAP);
    float*          bias0  = (float*)(ws + O_BIAS0);
    float*          bias1  = (float*)(ws + O_BIAS1);
    unsigned short* B0     = (unsigned short*)(ws + O_B0);
    unsigned short* B1     = (unsigned short*)(ws + O_B1);

    hipMemsetAsync(hist, 0, 512, stream);
    k_hist<<<16, 256, 0, stream>>>(len, hist);
    k_scan<<<1, 64, 0, stream>>>(hist);
    k_scatter<<<16, 256, 0, stream>>>(len, hist, rowmap);
    k_prep_bias<<<2, 256, 0, stream>>>(bih0, bhh0, bih1, bhh1, bias0, bias1);
    k_prep_b<<<(7 * 28672 + 255) / 256, 256, 0, stream>>>(Wih0, Whh0, Wih1, Whh1, B0, B1);
    k_lstm<<<256, 512, 0, stream>>>(x, len, rowmap, B0, B1, bias0, bias1, Wfc, bfc, out);
}

// Round 5
// 1046.408 us; speedup vs baseline: 1.3642x; 1.3642x over previous
//
#include <hip/hip_runtime.h>
#include <math.h>

// Problem constants (B=4096, T=100, F=13, H=100)
#define B_    4096
#define T_    100
#define F_    13
#define H_    100

typedef short bf16x8 __attribute__((ext_vector_type(8)));
typedef float f32x4  __attribute__((ext_vector_type(4)));

// ---- ws layout (bytes), total 651,264 ----
#define O_HIST   0u        // 512
#define O_ROWMAP 512u      // 4096*4
#define O_BIAS0  16896u    // 448*4
#define O_BIAS1  18688u    // 448*4
#define O_B0     20480u    // 4kt * 28672 u16 * 2B = 229376
#define O_B1     249856u   // 7kt * 28672 u16 * 2B = 401408 -> 651264

// B-fragment array layout (u16 units), per layer:
//   idx = (((kt*4 + g)*7 + ct)*2 + pass)*512 + lane*8 + j
// where lane's frag element j holds W_pass[k = kt*32 + (lane>>4)*8 + j]
//                                  [col = g*112 + ct*16 + (lane&15)]
// (cols are gate-major with H padded 100->112; pad cols/k are zero)

__device__ __forceinline__ float sigmoid_f(float v) {
    return 1.0f / (1.0f + __expf(-v));
}
__device__ __forceinline__ float tanh_f(float v) {
    float e = __expf(2.0f * v);
    return 1.0f - 2.0f / (e + 1.0f);
}
// fp32 -> bf16 hi (truncate) + lo (RNE of remainder): hi+lo ~ 2^-17 rel err
__device__ __forceinline__ void split_bf16(float v, unsigned short& hi, unsigned short& lo) {
    unsigned u = __float_as_uint(v);
    hi = (unsigned short)(u >> 16);
    float hf = __uint_as_float(u & 0xFFFF0000u);
    float rem = v - hf;
    unsigned r = __float_as_uint(rem);
    unsigned rnd = r + 0x7FFFu + ((r >> 16) & 1u);
    lo = (unsigned short)(rnd >> 16);
}
__device__ __forceinline__ float bf16_to_f(unsigned short b) {
    return __uint_as_float(((unsigned)b) << 16);
}

// async global->LDS, 16 B per lane. LDS dest = wave-uniform base + lane*16.
// Address-space casts via integer round-trip (generic LDS ptr low 32 bits are
// the LDS offset on gfx9xx; generic global == AS1).
__device__ __forceinline__ void gload16(const unsigned short* g, unsigned short* l) {
    __builtin_amdgcn_global_load_lds(
        (const __attribute__((address_space(1))) void*)(unsigned long long)g,
        (__attribute__((address_space(3))) void*)(unsigned)(unsigned long long)l,
        16, 0, 0);
}

// ---------------- prep: counting sort of rows by length ----------------
__global__ void k_hist(const int* __restrict__ len, int* __restrict__ hist) {
    int b = blockIdx.x * blockDim.x + threadIdx.x;
    if (b < B_) atomicAdd(&hist[len[b]], 1);
}
__global__ void k_scan(int* __restrict__ hist) {
    if (threadIdx.x == 0 && blockIdx.x == 0) {
        int acc = 0;
        for (int l = 0; l <= 100; ++l) { int c = hist[l]; hist[l] = acc; acc += c; }
    }
}
__global__ void k_scatter(const int* __restrict__ len, int* __restrict__ hist,
                          int* __restrict__ rowmap) {
    int b = blockIdx.x * blockDim.x + threadIdx.x;
    if (b < B_) {
        int pos = atomicAdd(&hist[len[b]], 1);
        rowmap[pos] = b;
    }
}

// ---------------- prep: biases (gate-major, padded) ----------------
__global__ void k_prep_bias(const float* __restrict__ bih0, const float* __restrict__ bhh0,
                            const float* __restrict__ bih1, const float* __restrict__ bhh1,
                            float* __restrict__ bias0, float* __restrict__ bias1) {
    int idx = blockIdx.x * blockDim.x + threadIdx.x;
    if (idx < 448) {
        int g = idx / 112, cell = idx % 112;
        float v0 = 0.f, v1 = 0.f;
        if (cell < 100) {
            int row = g * 100 + cell;
            v0 = bih0[row] + bhh0[row];
            v1 = bih1[row] + bhh1[row];
        }
        bias0[idx] = v0; bias1[idx] = v1;
    }
}

// ---------------- prep: weights into B-fragment order, bf16 hi/lo ----------
// Layer0 A-k: k<100 -> h0 (Whh0), 100..112 -> x (Wih0), >=113 -> 0
// Layer1 A-k: k<100 -> h0n (Wih1), 100..199 -> h1 (Whh1), >=200 -> 0
__global__ void k_prep_b(const float* __restrict__ Wih0, const float* __restrict__ Whh0,
                         const float* __restrict__ Wih1, const float* __restrict__ Whh1,
                         unsigned short* __restrict__ B0, unsigned short* __restrict__ B1) {
    const int PER_KT = 4 * 7 * 2 * 512;  // 28672 u16 per K-tile
    int idx = blockIdx.x * blockDim.x + threadIdx.x;
    if (idx >= 7 * PER_KT) return;
    int kt = idx / PER_KT;
    int s  = idx % PER_KT;
    int g  = s / 7168;
    int s2 = s % 7168;
    int ct = s2 / 1024;
    int s3 = s2 % 1024;
    int pass = s3 / 512;
    int e  = s3 % 512;
    int lane = e >> 3, j = e & 7;
    int n = lane & 15, q = lane >> 4;
    int k = kt * 32 + q * 8 + j;
    int cell = ct * 16 + n;

    unsigned short hi, lo;
    {   // layer 1
        float w = 0.f;
        if (cell < 100) {
            int row = g * 100 + cell;
            if (k < 100)      w = Wih1[row * 100 + k];
            else if (k < 200) w = Whh1[row * 100 + (k - 100)];
        }
        split_bf16(w, hi, lo);
        B1[idx] = pass ? lo : hi;
    }
    if (kt < 4) {  // layer 0
        float w = 0.f;
        if (cell < 100) {
            int row = g * 100 + cell;
            if (k < 100)      w = Whh0[row * 100 + k];
            else if (k < 113) w = Wih0[row * 13 + (k - 100)];
        }
        split_bf16(w, hi, lo);
        B0[idx] = pass ? lo : hi;
    }
}

// ---------------- main persistent MFMA LSTM ----------------
// v6: 256 blocks x 16 rows (v4 structure) + zero-VGPR async B staging:
//  * B fragments staged L2 -> LDS via __builtin_amdgcn_global_load_lds
//    (16 B/lane, wave-uniform LDS base + lane*16 = exactly our frag layout).
//    Per wave: double-buffered 8 KB kt-slices (8 frags: bh/bl x 4 gates).
//  * Counted s_waitcnt vmcnt(8): issue kt+1's 8 loads, then wait only for
//    kt's 8 -> a full kt of MFMAs+ds_reads (~150+ cyc) covers L2 latency,
//    with ZERO VGPRs held (v5's register double-buffer spilled at the
//    immovable 128-VGPR cap; FETCH 470 MB of scratch traffic proved it).
//  * Cross-phase prefetch: next phase's kt0 slice issued right after the
//    current GEMM loop; the barrier's vmcnt(0) drain lands it early.
//  * Buffer alternation: every stage flips nb; reads trail by exactly one
//    stage (hand-simulated t=0/t=1 incl. cross-phase; no overlap hazards:
//    a buffer's reads complete before the MFMAs that consume them issue,
//    which precedes the next stage into that buffer in program order).
//  * LDS: A-state 47104 B + staging 7*2*8192 = 114688 B -> ~162 KB (<160 KiB
//    limit 163840). 1 block/CU as before.
//  * MFMA order per accumulator unchanged -> bit-identical numerics
//    (absmax canary: 0.0001220703).
// Waves 0..6: cell-tile ct (cells 16ct..16ct+15), all 4 gates. Wave 7: x.
__global__ __attribute__((amdgpu_flat_work_group_size(512, 512), amdgpu_waves_per_eu(2, 2)))
void k_lstm(
    const float* __restrict__ x, const int* __restrict__ lengths,
    const int* __restrict__ rowmap,
    const unsigned short* __restrict__ B0, const unsigned short* __restrict__ B1,
    const float* __restrict__ bias0, const float* __restrict__ bias1,
    const float* __restrict__ Wfc, const float* __restrict__ bfc,
    float* __restrict__ out)
{
    // strides padded (+8 u16) so frag reads are 2-way-conflict max (free)
    __shared__ __align__(16) unsigned short Ah0[2][16 * 136];
    __shared__ __align__(16) unsigned short Al0[2][16 * 136];
    __shared__ __align__(16) unsigned short Ah1[2][16 * 232];
    __shared__ __align__(16) unsigned short Al1[2][16 * 232];
    __shared__ __align__(16) unsigned short Bst[7][2][4096];  // 8 frags/slice
    __shared__ int sRow[16], sLen[16], sTmax;

    const int tid = threadIdx.x;
    const int wv = tid >> 6, lane = tid & 63;

    if (tid < 16) {
        int r = rowmap[blockIdx.x * 16 + tid];
        sRow[tid] = r; sLen[tid] = lengths[r];
    }
    for (int i = tid; i < 16 * 136; i += 512) {
        Ah0[0][i] = 0; Al0[0][i] = 0; Ah0[1][i] = 0; Al0[1][i] = 0;
    }
    for (int i = tid; i < 16 * 232; i += 512) {
        Ah1[0][i] = 0; Al1[0][i] = 0; Ah1[1][i] = 0; Al1[1][i] = 0;
    }
    __syncthreads();   // (pre-1) sRow/sLen + zero-init published
    if (tid == 0) { int m = 0; for (int i = 0; i < 16; ++i) m = max(m, sLen[i]); sTmax = m; }

    // ---- per-wave setup ----
    const int ct = wv, n = lane & 15, q = lane >> 4;
    const int cell = ct * 16 + n;

    float b0v[4], b1v[4];
    int   lenR[4];
    float c0[4], c1[4];
    int offA0, offA1;
    const unsigned short* B0w = B0 + ct * 1024 + lane * 8;
    const unsigned short* B1w = B1 + ct * 1024 + lane * 8;
    int nb = 0;   // next staging buffer (per-wave uniform)
    if (wv < 7) {
#pragma unroll
        for (int g = 0; g < 4; ++g) {
            b0v[g] = bias0[g * 112 + cell];
            b1v[g] = bias1[g * 112 + cell];
        }
        offA0 = n * 136 + q * 8;
        offA1 = n * 232 + q * 8;
#pragma unroll
        for (int r = 0; r < 4; ++r) {
            lenR[r] = sLen[q * 4 + r];       // C row = q*4 + r
            c0[r] = 0.f; c1[r] = 0.f;
        }
        // initial stage: L0 kt0 -> buf 0 (lands before the first barrier drain)
#pragma unroll
        for (int g = 0; g < 4; ++g) {
            gload16(B0w + (size_t)g * 7168,       &Bst[wv][0][(2 * g) * 512]);
            gload16(B0w + (size_t)g * 7168 + 512, &Bst[wv][0][(2 * g + 1) * 512]);
        }
        nb = 1;
    }

    // wave 7: x loader (16 rows x 13 feats = 208 slots, 4 per lane)
    int xvalid[4]; size_t xg[4]; int xa[4]; float xv[4];
    if (wv == 7) {
#pragma unroll
        for (int i = 0; i < 4; ++i) {
            int e = i * 64 + lane;
            xvalid[i] = (e < 208);
            int r = xvalid[i] ? (e / 13) : 0;
            int f = xvalid[i] ? (e - 13 * r) : 0;
            xg[i] = (size_t)sRow[r] * (T_ * F_) + f;
            xa[i] = r * 136 + 100 + f;
            xv[i] = xvalid[i] ? x[xg[i]] : 0.f;   // t = 0
        }
    }
    __syncthreads();   // (pre-2) sTmax published; zero-init done everywhere
    const int Tmax = sTmax;
    if (wv == 7) {     // write x_0 into buffer 0
#pragma unroll
        for (int i = 0; i < 4; ++i) if (xvalid[i]) {
            unsigned short hi, lo; split_bf16(xv[i], hi, lo);
            Ah0[0][xa[i]] = hi; Al0[0][xa[i]] = lo;
        }
    }
    __syncthreads();   // (pre-3) x_0 published (drains staging too)

    for (int t = 0; t < Tmax; ++t) {
        const int p = t & 1, pn = p ^ 1;
        // =============== phase 1: layer-0 (reads A0[p]) ===============
        if (wv < 7) {
            f32x4 P[4];
#pragma unroll
            for (int g = 0; g < 4; ++g)
                P[g] = (f32x4){b0v[g], b0v[g], b0v[g], b0v[g]};
            int cur = nb ^ 1;                 // buffer holding kt0's slice
#pragma unroll
            for (int kt = 0; kt < 4; ++kt) {
                if (kt + 1 < 4) {             // stage kt+1, then wait for kt
#pragma unroll
                    for (int g = 0; g < 4; ++g) {
                        gload16(B0w + (size_t)((kt + 1) * 4 + g) * 7168,
                                &Bst[wv][nb][(2 * g) * 512]);
                        gload16(B0w + (size_t)((kt + 1) * 4 + g) * 7168 + 512,
                                &Bst[wv][nb][(2 * g + 1) * 512]);
                    }
                    nb ^= 1;
                    asm volatile("s_waitcnt vmcnt(8)" ::: "memory");
                } else {
                    asm volatile("s_waitcnt vmcnt(0)" ::: "memory");
                }
                const unsigned short* sl = &Bst[wv][cur][lane * 8];
                cur ^= 1;
                bf16x8 ah = *(const bf16x8*)&Ah0[p][offA0 + kt * 32];
                bf16x8 al = *(const bf16x8*)&Al0[p][offA0 + kt * 32];
#pragma unroll
                for (int g = 0; g < 4; ++g) {
                    bf16x8 bhf = *(const bf16x8*)&sl[(2 * g) * 512];
                    bf16x8 blf = *(const bf16x8*)&sl[(2 * g + 1) * 512];
                    f32x4 acc = P[g];
                    acc = __builtin_amdgcn_mfma_f32_16x16x32_bf16(ah, blf, acc, 0, 0, 0);
                    acc = __builtin_amdgcn_mfma_f32_16x16x32_bf16(al, bhf, acc, 0, 0, 0);
                    acc = __builtin_amdgcn_mfma_f32_16x16x32_bf16(ah, bhf, acc, 0, 0, 0);
                    P[g] = acc;
                }
            }
            // cross-phase prefetch: L1 kt0 (latency hidden by pointwise+barrier)
#pragma unroll
            for (int g = 0; g < 4; ++g) {
                gload16(B1w + (size_t)g * 7168,       &Bst[wv][nb][(2 * g) * 512]);
                gload16(B1w + (size_t)g * 7168 + 512, &Bst[wv][nb][(2 * g + 1) * 512]);
            }
            nb ^= 1;
            // pointwise + state update
            float hreg[4];
#pragma unroll
            for (int r = 0; r < 4; ++r) {
                float zi = P[0][r];
                float zf = P[1][r];
                float zg = P[2][r];
                float zo = P[3][r];
                float cn = sigmoid_f(zf) * c0[r] + sigmoid_f(zi) * tanh_f(zg);
                float hn = sigmoid_f(zo) * tanh_f(cn);
                if (t < lenR[r]) c0[r] = cn;
                hreg[r] = hn;
            }
            // h0n -> A0[pn] (for GEMM0 at t+1) and A1[p] (for GEMM1 this step)
            if (cell < 100) {
#pragma unroll
                for (int r = 0; r < 4; ++r) {
                    if (t < lenR[r]) {
                        int m = q * 4 + r;
                        unsigned short hi, lo; split_bf16(hreg[r], hi, lo);
                        Ah0[pn][m * 136 + cell] = hi; Al0[pn][m * 136 + cell] = lo;
                        Ah1[p][m * 232 + cell]  = hi; Al1[p][m * 232 + cell]  = lo;
                    }
                }
            }
        } else {
            // wave 7: load x(t+1) and write into A0[pn] (read next at t+1)
            if (t + 1 < Tmax) {
#pragma unroll
                for (int i = 0; i < 4; ++i)
                    if (xvalid[i]) xv[i] = x[xg[i] + (size_t)(t + 1) * F_];
#pragma unroll
                for (int i = 0; i < 4; ++i) if (xvalid[i]) {
                    unsigned short hi, lo; split_bf16(xv[i], hi, lo);
                    Ah0[pn][xa[i]] = hi; Al0[pn][xa[i]] = lo;
                }
            }
        }
        __syncthreads();   // (A) h0n published in A1[p]; L1 kt0 staged
        // =============== phase 2: layer-1 (reads A1[p]) ===============
        if (wv < 7) {
            f32x4 P[4];
#pragma unroll
            for (int g = 0; g < 4; ++g)
                P[g] = (f32x4){b1v[g], b1v[g], b1v[g], b1v[g]};
            int cur = nb ^ 1;
#pragma unroll
            for (int kt = 0; kt < 7; ++kt) {
                if (kt + 1 < 7) {
#pragma unroll
                    for (int g = 0; g < 4; ++g) {
                        gload16(B1w + (size_t)((kt + 1) * 4 + g) * 7168,
                                &Bst[wv][nb][(2 * g) * 512]);
                        gload16(B1w + (size_t)((kt + 1) * 4 + g) * 7168 + 512,
                                &Bst[wv][nb][(2 * g + 1) * 512]);
                    }
                    nb ^= 1;
                    asm volatile("s_waitcnt vmcnt(8)" ::: "memory");
                } else {
                    asm volatile("s_waitcnt vmcnt(0)" ::: "memory");
                }
                const unsigned short* sl = &Bst[wv][cur][lane * 8];
                cur ^= 1;
                bf16x8 ah = *(const bf16x8*)&Ah1[p][offA1 + kt * 32];
                bf16x8 al = *(const bf16x8*)&Al1[p][offA1 + kt * 32];
#pragma unroll
                for (int g = 0; g < 4; ++g) {
                    bf16x8 bhf = *(const bf16x8*)&sl[(2 * g) * 512];
                    bf16x8 blf = *(const bf16x8*)&sl[(2 * g + 1) * 512];
                    f32x4 acc = P[g];
                    acc = __builtin_amdgcn_mfma_f32_16x16x32_bf16(ah, blf, acc, 0, 0, 0);
                    acc = __builtin_amdgcn_mfma_f32_16x16x32_bf16(al, bhf, acc, 0, 0, 0);
                    acc = __builtin_amdgcn_mfma_f32_16x16x32_bf16(ah, bhf, acc, 0, 0, 0);
                    P[g] = acc;
                }
            }
            // cross-phase prefetch: L0 kt0 for t+1 (harmless at last t)
#pragma unroll
            for (int g = 0; g < 4; ++g) {
                gload16(B0w + (size_t)g * 7168,       &Bst[wv][nb][(2 * g) * 512]);
                gload16(B0w + (size_t)g * 7168 + 512, &Bst[wv][nb][(2 * g + 1) * 512]);
            }
            nb ^= 1;
            float hreg[4];
#pragma unroll
            for (int r = 0; r < 4; ++r) {
                float zi = P[0][r];
                float zf = P[1][r];
                float zg = P[2][r];
                float zo = P[3][r];
                float cn = sigmoid_f(zf) * c1[r] + sigmoid_f(zi) * tanh_f(zg);
                float hn = sigmoid_f(zo) * tanh_f(cn);
                if (t < lenR[r]) c1[r] = cn;
                hreg[r] = hn;
            }
            // h1n -> A1[pn] (read at t+1); frozen rows keep last value in
            // buffer (len&1)
            if (cell < 100) {
#pragma unroll
                for (int r = 0; r < 4; ++r) {
                    if (t < lenR[r]) {
                        int m = q * 4 + r;
                        unsigned short hi, lo; split_bf16(hreg[r], hi, lo);
                        Ah1[pn][m * 232 + 100 + cell] = hi;
                        Al1[pn][m * 232 + 100 + cell] = lo;
                    }
                }
            }
        }
        __syncthreads();   // (B) A0[pn] (h0n+x) and A1[pn] (h1n) published
    }

    // final: out[b] = W_fc . h1 + b_fc  (h1 = hi+lo, frozen at len-1; it lives
    // in buffer len&1 since the last write at t=len-1 targeted parity (len-1)^1)
    if (tid < 16) {
        const int par = sLen[tid] & 1;
        float s = bfc[0];
        for (int j = 0; j < 100; ++j) {
            float h = bf16_to_f(Ah1[par][tid * 232 + 100 + j]) +
                      bf16_to_f(Al1[par][tid * 232 + 100 + j]);
            s = fmaf(Wfc[j], h, s);
        }
        out[sRow[tid]] = s;
    }
}

// ---------------- launch ----------------
extern "C" void kernel_launch(void* const* d_in, const int* in_sizes, int n_in,
                              void* d_out, int out_size, void* d_ws, size_t ws_size,
                              hipStream_t stream) {
    const float* x    = (const float*)d_in[0];
    const int*   len  = (const int*)d_in[1];
    const float* Wih0 = (const float*)d_in[2];
    const float* Whh0 = (const float*)d_in[3];
    const float* bih0 = (const float*)d_in[4];
    const float* bhh0 = (const float*)d_in[5];
    const float* Wih1 = (const float*)d_in[6];
    const float* Whh1 = (const float*)d_in[7];
    const float* bih1 = (const float*)d_in[8];
    const float* bhh1 = (const float*)d_in[9];
    const float* Wfc  = (const float*)d_in[10];
    const float* bfc  = (const float*)d_in[11];
    float* out = (float*)d_out;

    char* ws = (char*)d_ws;   // uses 651,264 bytes
    int*            hist   = (int*)(ws + O_HIST);
    int*            rowmap = (int*)(ws + O_ROWMAP);
    float*          bias0  = (float*)(ws + O_BIAS0);
    float*          bias1  = (float*)(ws + O_BIAS1);
    unsigned short* B0     = (unsigned short*)(ws + O_B0);
    unsigned short* B1     = (unsigned short*)(ws + O_B1);

    hipMemsetAsync(hist, 0, 512, stream);
    k_hist<<<16, 256, 0, stream>>>(len, hist);
    k_scan<<<1, 64, 0, stream>>>(hist);
    k_scatter<<<16, 256, 0, stream>>>(len, hist, rowmap);
    k_prep_bias<<<2, 256, 0, stream>>>(bih0, bhh0, bih1, bhh1, bias0, bias1);
    k_prep_b<<<(7 * 28672 + 255) / 256, 256, 0, stream>>>(Wih0, Whh0, Wih1, Whh1, B0, B1);
    k_lstm<<<256, 512, 0, stream>>>(x, len, rowmap, B0, B1, bias0, bias1, Wfc, bfc, out);
}